// Round 1
// baseline (224.695 us; speedup 1.0000x reference)
//
#include <hip/hip_runtime.h>
#include <math.h>

#define L    2048
#define NCOL 4096
#define NG   1024
#define N3   3072
#define T    512
#define NW   8            // waves per block
#define EPT  8            // NCOL / T
#define NB   2048         // buckets (exact: floor(x*2048), power-of-two mult)
#define FEPS 1.1920929e-07f

typedef unsigned long long u64;
typedef unsigned short u16;
typedef unsigned int u32;

__device__ __forceinline__ int lower_bound_f(const float* a, int lo, int hi, float v) {
  // exact replica of numpy's npy_binsearch (side='left') on [lo,hi)
  while (lo < hi) {
    int mid = (lo + hi) >> 1;
    if (a[mid] < v) lo = mid + 1; else hi = mid;
  }
  return lo;
}

__device__ __forceinline__ int bucket_of_bits(unsigned xb) {
  float f = __uint_as_float(xb);
  int b = (int)(f * (float)NB);          // exact: mult by 2^11
  return b > NB - 1 ? NB - 1 : b;
}

// XOR swizzle for the w/y plane: spreads the stride-32B cumsum access
// (bank = 8t+c -> 8-way) across all 32 banks (2-way = free). Bijective.
__device__ __forceinline__ int swz(int i) { return i ^ ((i >> 5) & 7); }

// LDS layout (37,392 B dynamic -> 4 blocks/CU, 32 waves/CU):
//   [0,32768)      pairs u64[4096] during scatter+rank; then xs f32[4096] @0,
//                  wy f32[4096] @16384 (sorted w, then in-place CDF ys)
//   [16384,28672)  ecdf f32[3072] overlays wy AFTER stage-1 (wy dead by then)
//   [32768,36872)  cnt u16[2050] (packed u32 words for atomics), padded
//   [36872,37392)  lut2 u16[257]
__global__ __launch_bounds__(T, 8) void lcot_rows(const float* __restrict__ X,
                                                  const float* __restrict__ W,
                                                  float* __restrict__ rowsum) {
  extern __shared__ char smem[];
  u64*   pairs = (u64*)smem;
  float* xs    = (float*)smem;
  float* wy    = (float*)(smem + 16384);
  float* ecdf  = (float*)(smem + 16384);          // overlay, used after stage-1
  u16*   cnt16 = (u16*)(smem + 32768);
  u32*   cntw  = (u32*)(smem + 32768);
  u16*   lut2  = (u16*)(smem + 36872);

  __shared__ float redA[NW], redB[NW], fwt[NW];
  __shared__ int   iwt[NW];
  __shared__ float s_alpha;

  const int tid  = threadIdx.x;
  const int lane = tid & 63;
  const int wave = tid >> 6;
  const int row  = blockIdx.x;
  const float* xr = X + (size_t)row * NCOL;
  const float* wr = W + (size_t)row * NCOL;

  // ---- zero packed histogram (1025 u32 words incl. sentinel word) ----
  for (int i = tid; i < 1025; i += T) cntw[i] = 0u;

  // ---- load 8 consecutive elems, pack stable keys, alpha partials ----
  u64 key[EPT];
  float sxw = 0.f, sw = 0.f;
  const float4* xr4 = (const float4*)xr;
  const float4* wr4 = (const float4*)wr;
#pragma unroll
  for (int c = 0; c < 2; ++c) {
    float4 xv = xr4[tid * 2 + c];
    float4 ww = wr4[tid * 2 + c];
    sxw += xv.x * ww.x + xv.y * ww.y + xv.z * ww.z + xv.w * ww.w;
    sw  += ww.x + ww.y + ww.z + ww.w;
    int b = 8 * tid + 4 * c;
    key[4*c+0] = ((u64)__float_as_uint(xv.x) << 32) | (unsigned)(b + 0);
    key[4*c+1] = ((u64)__float_as_uint(xv.y) << 32) | (unsigned)(b + 1);
    key[4*c+2] = ((u64)__float_as_uint(xv.z) << 32) | (unsigned)(b + 2);
    key[4*c+3] = ((u64)__float_as_uint(xv.w) << 32) | (unsigned)(b + 3);
  }
#pragma unroll
  for (int off = 32; off > 0; off >>= 1) {
    sxw += __shfl_down(sxw, off);
    sw  += __shfl_down(sw, off);
  }
  if (lane == 0) { redA[wave] = sxw; redB[wave] = sw; }
  __syncthreads();   // [1] zeroed cnt + redA/redB visible

  // ---- histogram on packed u16 fields: ord from atomic return ----
  int ord[EPT];
#pragma unroll
  for (int e = 0; e < EPT; ++e) {
    int b = bucket_of_bits((unsigned)(key[e] >> 32));
    u32 inc = (b & 1) ? 65536u : 1u;
    u32 ret = atomicAdd(&cntw[b >> 1], inc);
    ord[e] = (b & 1) ? (int)(ret >> 16) : (int)(ret & 0xffffu);
  }
  __syncthreads();   // [2] all atomics done
  if (tid == 0) {
    float a = 0.f, b = 0.f;
#pragma unroll
    for (int i = 0; i < NW; ++i) { a += redA[i]; b += redB[i]; }
    s_alpha = a / b - 0.5f;
  }

  // ---- exclusive scan of 2048 u16 counts -> bases (packed, in place) ----
  u32 cv0 = cntw[2 * tid], cv1 = cntw[2 * tid + 1];
  int c0 = (int)(cv0 & 0xffffu), c1 = (int)(cv0 >> 16);
  int c2 = (int)(cv1 & 0xffffu), c3 = (int)(cv1 >> 16);
  int runi = c0 + c1 + c2 + c3;
  int toti = runi, prei = runi;
#pragma unroll
  for (int off = 1; off < 64; off <<= 1) {
    int v = __shfl_up(prei, off);
    if (lane >= off) prei += v;
  }
  if (lane == 63) iwt[wave] = prei;
  __syncthreads();   // [3] iwt visible (each thread only rewrites its own words)
  int wpre = 0;
#pragma unroll
  for (int w2 = 0; w2 < NW; ++w2) wpre += (w2 < wave) ? iwt[w2] : 0;
  int acc = wpre + prei - toti;
  {
    int b0 = acc; acc += c0;
    int b1 = acc; acc += c1;
    int b2 = acc; acc += c2;
    int b3 = acc; acc += c3;
    cntw[2 * tid]     = (u32)b0 | ((u32)b1 << 16);
    cntw[2 * tid + 1] = (u32)b2 | ((u32)b3 << 16);
  }
  if (tid == T - 1) cnt16[NB] = (u16)acc;   // sentinel = 4096
  __syncthreads();   // [4] bases visible

  // ---- scatter keys into bucket slots (arrival order) ----
#pragma unroll
  for (int e = 0; e < EPT; ++e) {
    int b = bucket_of_bits((unsigned)(key[e] >> 32));
    pairs[(int)cnt16[b] + ord[e]] = key[e];
  }
  __syncthreads();   // [5]

  // ---- rank within bucket: unique u64 keys -> slot = base + #smaller ----
  // Predicated 4 reads (covers 95% of Poisson(2) buckets), independent ->
  // fully pipelined across the 8 keys. Rare tail pass for n>4. Exactly the
  // stable (xbits, idx) order the insertion sort produced.
  int dst[EPT]; int tailhi[EPT];
#pragma unroll
  for (int e = 0; e < EPT; ++e) {
    int b = bucket_of_bits((unsigned)(key[e] >> 32));
    int lo = (int)cnt16[b], hi = (int)cnt16[b + 1];
    int hm1 = hi - 1;
    u64 k = key[e];
    u64 p0 = pairs[lo];
    u64 p1 = pairs[lo + 1 < hm1 ? lo + 1 : hm1];
    u64 p2 = pairs[lo + 2 < hm1 ? lo + 2 : hm1];
    u64 p3 = pairs[lo + 3 < hm1 ? lo + 3 : hm1];
    int n = hi - lo;
    int r = (int)(p0 < k) + (int)(n > 1 && p1 < k)
          + (int)(n > 2 && p2 < k) + (int)(n > 3 && p3 < k);
    dst[e] = lo + r;
    tailhi[e] = (n > 4) ? hi : 0;    // encode hi when a tail scan is needed
  }
#pragma unroll
  for (int e = 0; e < EPT; ++e) {
    if (tailhi[e]) {                 // rare: bucket larger than 4
      int b = bucket_of_bits((unsigned)(key[e] >> 32));
      int lo = (int)cnt16[b];
      u64 k = key[e];
      int r = 0;
      for (int j2 = lo + 4; j2 < tailhi[e]; ++j2) r += (int)(pairs[j2] < k);
      dst[e] += r;
    }
  }

  // re-load own w's (coalesced, L2-resident) while ranks settle
  float4 wv0 = wr4[tid * 2], wv1 = wr4[tid * 2 + 1];
  __syncthreads();   // [6] all pairs reads done before aliasing xs/wy writes

  // ---- scatter (x, w) directly to sorted slots (no sorted-pairs pass,
  //      no global gather) ----
  {
    float wv[EPT] = {wv0.x, wv0.y, wv0.z, wv0.w, wv1.x, wv1.y, wv1.z, wv1.w};
#pragma unroll
    for (int e = 0; e < EPT; ++e) {
      int d = dst[e];
      xs[d]       = __uint_as_float((u32)(key[e] >> 32));
      wy[swz(d)]  = wv[e];
    }
  }
  __syncthreads();   // [7] sorted xs/w visible

  // ---- cumsum weights (read own 8 sorted slots, swizzled = conflict-free) ----
  float lw[EPT];
  float runf = 0.f;
#pragma unroll
  for (int c = 0; c < EPT; ++c) {
    float wv = wy[swz(8 * tid + c)];
    runf += wv; lw[c] = runf;
  }
  float totf = runf, pref = runf;
#pragma unroll
  for (int off = 1; off < 64; off <<= 1) {
    float v = __shfl_up(pref, off);
    if (lane >= off) pref += v;
  }
  if (lane == 63) fwt[wave] = pref;
  __syncthreads();   // [8] fwt visible
  float wpf = 0.f;
#pragma unroll
  for (int w2 = 0; w2 < NW; ++w2) wpf += (w2 < wave) ? fwt[w2] : 0.f;
  float basef = wpf + pref - totf;
#pragma unroll
  for (int c = 0; c < EPT; ++c) wy[swz(8 * tid + c)] = basef + lw[c];
  __syncthreads();   // [9] xs + CDF visible

  // ---- stage 1: ecdf values into REGISTERS (bucket bases = exact brackets) ----
  // Predicated count over the (sorted) bucket == lower_bound; no divergent
  // loop, so the 6 independent queries pipeline.
  float ev[N3 / T];
  int lb1[N3 / T], lo1[N3 / T], n1[N3 / T];
#pragma unroll
  for (int s = 0; s < N3 / T; ++s) {
    int j = tid + s * T;
    float xnew = -1.0f + (3.0f * (float)j) / 3071.0f;
    float rest = xnew - floorf(xnew);            // in [0,1)
    int k = (int)(rest * (float)NB);             // exact
    k = k > NB - 1 ? NB - 1 : k;
    int lo = (int)cnt16[k], hi = (int)cnt16[k + 1];
    int n = hi - lo;
    float a0 = xs[lo + 0 < NCOL - 1 ? lo + 0 : NCOL - 1];
    float a1 = xs[lo + 1 < NCOL - 1 ? lo + 1 : NCOL - 1];
    float a2 = xs[lo + 2 < NCOL - 1 ? lo + 2 : NCOL - 1];
    float a3 = xs[lo + 3 < NCOL - 1 ? lo + 3 : NCOL - 1];
    int c = (int)(n > 0 && a0 < rest) + (int)(n > 1 && a1 < rest)
          + (int)(n > 2 && a2 < rest) + (int)(n > 3 && a3 < rest);
    lb1[s] = lo + c;
    lo1[s] = lo; n1[s] = n;
  }
#pragma unroll
  for (int s = 0; s < N3 / T; ++s) {
    if (n1[s] > 4 && lb1[s] == lo1[s] + 4) {     // rare: first 4 all < rest
      int j = tid + s * T;
      float xnew = -1.0f + (3.0f * (float)j) / 3071.0f;
      float rest = xnew - floorf(xnew);
      int hi = lo1[s] + n1[s];
      int p = lo1[s] + 4;
      while (p < hi && xs[p] < rest) ++p;
      lb1[s] = p;
    }
  }
#pragma unroll
  for (int s = 0; s < N3 / T; ++s) {
    int j = tid + s * T;
    float xnew = -1.0f + (3.0f * (float)j) / 3071.0f;
    float ix = floorf(xnew);
    float rest = xnew - ix;
    int ind = lb1[s] - 1;
    ind = ind < 0 ? 0 : (ind > NCOL - 2 ? NCOL - 2 : ind);
    float x0 = xs[ind], x1v = xs[ind + 1];
    float y0 = wy[swz(ind)], y1v = wy[swz(ind + 1)];
    float slope = (y1v - y0) * __builtin_amdgcn_rcpf(FEPS + (x1v - x0));
    ev[s] = ix + (y0 + slope * (rest - x0));
  }
  __syncthreads();   // [10] all xs/wy reads done -> wy region reusable

  // ---- write ecdf overlay (over dead wy region) ----
#pragma unroll
  for (int s = 0; s < N3 / T; ++s) ecdf[tid + s * T] = ev[s];
  __syncthreads();   // [11]

  // ---- stage-2 value LUT over ecdf range [-1,2): 257 brackets ----
  if (tid < 257) {
    float v = -1.0f + 3.0f * (float)tid * (1.0f / 256.0f);
    lut2[tid] = (u16)lower_bound_f(ecdf, 0, N3, v);
  }
  __syncthreads();   // [12]

  // ---- stage 2: inverse-CDF embedding + circular cost partial sum ----
  float alpha = s_alpha;
  float accf = 0.f;
#pragma unroll
  for (int s = 0; s < NG / T; ++s) {
    int kq = tid + s * T;
    float xg = (float)kq / 1024.0f;
    float q2 = xg - alpha;
    int k2 = (int)floorf((q2 + 1.0f) * (256.0f / 3.0f));
    k2 = k2 < 0 ? 0 : (k2 > 255 ? 255 : k2);
    int blo = k2 > 0 ? k2 - 1 : 0;           // widen +-1: immune to fp rounding of k2
    int bhi = k2 < 254 ? k2 + 2 : 256;
    int lo = lower_bound_f(ecdf, (int)lut2[blo], (int)lut2[bhi], q2);
    int ind = lo - 1;
    ind = ind < 0 ? 0 : (ind > N3 - 2 ? N3 - 2 : ind);
    float e0 = ecdf[ind], e1 = ecdf[ind + 1];
    float y0 = -1.0f + (3.0f * (float)ind) / 3071.0f;
    float y1 = -1.0f + (3.0f * (float)(ind + 1)) / 3071.0f;
    float slope = (y1 - y0) * __builtin_amdgcn_rcpf(FEPS + (e1 - e0));
    float emb = y0 + slope * (q2 - e0) - xg;
    float a = fabsf(emb);
    float m = fminf(a, 1.0f - a);
    accf += m * m;
  }
#pragma unroll
  for (int off = 32; off > 0; off >>= 1) accf += __shfl_down(accf, off);
  if (lane == 0) redA[wave] = accf;
  __syncthreads();   // [13]
  if (tid == 0) {
    float s = 0.f;
#pragma unroll
    for (int i = 0; i < NW; ++i) s += redA[i];
    rowsum[row] = s;
  }
}

__global__ __launch_bounds__(256) void lcot_final(const float* __restrict__ rowsum,
                                                  float* __restrict__ out) {
  __shared__ float red[4];
  int t = threadIdx.x;
  float s = 0.f;
  for (int i = t; i < L; i += 256) s += rowsum[i];
#pragma unroll
  for (int off = 32; off > 0; off >>= 1) s += __shfl_down(s, off);
  if ((t & 63) == 0) red[t >> 6] = s;
  __syncthreads();
  if (t == 0) {
    float tot = red[0] + red[1] + red[2] + red[3];
    out[0] = sqrtf(tot / (float)L + 1e-8f);
  }
}

extern "C" void kernel_launch(void* const* d_in, const int* in_sizes, int n_in,
                              void* d_out, int out_size, void* d_ws, size_t ws_size,
                              hipStream_t stream) {
  const float* X = (const float*)d_in[0];
  const float* W = (const float*)d_in[1];
  float* rowsum = (float*)d_ws;  // 2048 floats
  // 32768 (pairs/xs/wy, ecdf overlays wy) + 4104 (u16 cnt) + 520 (lut2) = 37,392 B
  size_t shbytes = 32768 + 4104 + 520;
  hipLaunchKernelGGL(lcot_rows, dim3(L), dim3(T), shbytes, stream, X, W, rowsum);
  hipLaunchKernelGGL(lcot_final, dim3(1), dim3(256), 0, stream,
                     (const float*)rowsum, (float*)d_out);
}

// Round 2
// 192.486 us; speedup vs baseline: 1.1673x; 1.1673x over previous
//
#include <hip/hip_runtime.h>
#include <math.h>

#define L    2048
#define NCOL 4096
#define NG   1024
#define N3   3072
#define T    512
#define NW   8            // waves per block
#define EPT  8            // NCOL / T
#define NB   2048         // buckets (exact: floor(x*2048), power-of-two mult)
#define FEPS 1.1920929e-07f

typedef unsigned long long u64;
typedef unsigned short u16;
typedef unsigned int u32;

__device__ __forceinline__ int lower_bound_f(const float* a, int lo, int hi, float v) {
  // exact replica of numpy's npy_binsearch (side='left') on [lo,hi)
  while (lo < hi) {
    int mid = (lo + hi) >> 1;
    if (a[mid] < v) lo = mid + 1; else hi = mid;
  }
  return lo;
}

__device__ __forceinline__ int bucket_of_bits(unsigned xb) {
  float f = __uint_as_float(xb);
  int b = (int)(f * (float)NB);          // exact: mult by 2^11
  return b > NB - 1 ? NB - 1 : b;
}

// XOR swizzle for the w/y plane: spreads the stride-32B cumsum access
// (bank = 8t+c -> 8-way) across all 32 banks (2-way = free). Bijective.
__device__ __forceinline__ int swz(int i) { return i ^ ((i >> 5) & 7); }

// LDS layout (37,392 B dynamic -> 4 blocks/CU, 32 waves/CU):
//   [0,32768)      pairs u64[4096] during scatter+rank; then xs f32[4096] @0,
//                  wy f32[4096] @16384 (sorted w, then in-place CDF ys)
//   [16384,28672)  ecdf f32[3072] overlays wy AFTER stage-1 (wy dead by then)
//   [32768,36872)  cnt u16[2050] (packed u32 words for atomics), padded
//   [36872,37392)  lut2 u16[257]
__global__ __launch_bounds__(T, 8) void lcot_rows(const float* __restrict__ X,
                                                  const float* __restrict__ W,
                                                  float* __restrict__ rowsum) {
  extern __shared__ char smem[];
  u64*   pairs = (u64*)smem;
  float* xs    = (float*)smem;
  float* wy    = (float*)(smem + 16384);
  float* ecdf  = (float*)(smem + 16384);          // overlay, used after stage-1
  u16*   cnt16 = (u16*)(smem + 32768);
  u32*   cntw  = (u32*)(smem + 32768);
  u16*   lut2  = (u16*)(smem + 36872);

  __shared__ float redA[NW], redB[NW], fwt[NW];
  __shared__ int   iwt[NW];
  __shared__ float s_alpha;

  const int tid  = threadIdx.x;
  const int lane = tid & 63;
  const int wave = tid >> 6;
  const int row  = blockIdx.x;
  const float* xr = X + (size_t)row * NCOL;
  const float* wr = W + (size_t)row * NCOL;

  // ---- zero packed histogram (1025 u32 words incl. sentinel word) ----
  for (int i = tid; i < 1025; i += T) cntw[i] = 0u;

  // ---- load 8 consecutive elems, pack stable keys, alpha partials ----
  u64 key[EPT];
  float sxw = 0.f, sw = 0.f;
  const float4* xr4 = (const float4*)xr;
  const float4* wr4 = (const float4*)wr;
#pragma unroll
  for (int c = 0; c < 2; ++c) {
    float4 xv = xr4[tid * 2 + c];
    float4 ww = wr4[tid * 2 + c];
    sxw += xv.x * ww.x + xv.y * ww.y + xv.z * ww.z + xv.w * ww.w;
    sw  += ww.x + ww.y + ww.z + ww.w;
    int b = 8 * tid + 4 * c;
    key[4*c+0] = ((u64)__float_as_uint(xv.x) << 32) | (unsigned)(b + 0);
    key[4*c+1] = ((u64)__float_as_uint(xv.y) << 32) | (unsigned)(b + 1);
    key[4*c+2] = ((u64)__float_as_uint(xv.z) << 32) | (unsigned)(b + 2);
    key[4*c+3] = ((u64)__float_as_uint(xv.w) << 32) | (unsigned)(b + 3);
  }
#pragma unroll
  for (int off = 32; off > 0; off >>= 1) {
    sxw += __shfl_down(sxw, off);
    sw  += __shfl_down(sw, off);
  }
  if (lane == 0) { redA[wave] = sxw; redB[wave] = sw; }
  __syncthreads();   // [1] zeroed cnt + redA/redB visible

  // ---- histogram on packed u16 fields; pack (bucket, ord) into one word ----
  u32 bo[EPT];
#pragma unroll
  for (int e = 0; e < EPT; ++e) {
    int b = bucket_of_bits((unsigned)(key[e] >> 32));
    u32 inc = (b & 1) ? 65536u : 1u;
    u32 ret = atomicAdd(&cntw[b >> 1], inc);
    u32 o = (b & 1) ? (ret >> 16) : (ret & 0xffffu);
    bo[e] = ((u32)b << 16) | (o & 0xffffu);
  }
  __syncthreads();   // [2] all atomics done
  if (tid == 0) {
    float a = 0.f, b = 0.f;
#pragma unroll
    for (int i = 0; i < NW; ++i) { a += redA[i]; b += redB[i]; }
    s_alpha = a / b - 0.5f;
  }

  // ---- exclusive scan of 2048 u16 counts -> bases (packed, in place) ----
  u32 cv0 = cntw[2 * tid], cv1 = cntw[2 * tid + 1];
  int c0 = (int)(cv0 & 0xffffu), c1 = (int)(cv0 >> 16);
  int c2 = (int)(cv1 & 0xffffu), c3 = (int)(cv1 >> 16);
  int runi = c0 + c1 + c2 + c3;
  int toti = runi, prei = runi;
#pragma unroll
  for (int off = 1; off < 64; off <<= 1) {
    int v = __shfl_up(prei, off);
    if (lane >= off) prei += v;
  }
  if (lane == 63) iwt[wave] = prei;
  __syncthreads();   // [3] iwt visible (each thread only rewrites its own words)
  int wpre = 0;
#pragma unroll
  for (int w2 = 0; w2 < NW; ++w2) wpre += (w2 < wave) ? iwt[w2] : 0;
  int acc = wpre + prei - toti;
  {
    int b0 = acc; acc += c0;
    int b1 = acc; acc += c1;
    int b2 = acc; acc += c2;
    int b3 = acc; acc += c3;
    cntw[2 * tid]     = (u32)b0 | ((u32)b1 << 16);
    cntw[2 * tid + 1] = (u32)b2 | ((u32)b3 << 16);
  }
  if (tid == T - 1) cnt16[NB] = (u16)acc;   // sentinel = 4096
  __syncthreads();   // [4] bases visible

  // ---- scatter keys into bucket slots (arrival order) ----
#pragma unroll
  for (int e = 0; e < EPT; ++e) {
    int b = (int)(bo[e] >> 16);
    int o = (int)(bo[e] & 0xffffu);
    pairs[(int)cnt16[b] + o] = key[e];
  }
  __syncthreads();   // [5]

  // ---- rank within bucket: unique u64 keys -> slot = base + #smaller ----
  // Predicated 4 reads (covers 95% of Poisson(2) buckets), inline rare tail.
  // Exactly the stable (xbits, idx) order an insertion sort would produce.
  int dst[EPT];
#pragma unroll
  for (int e = 0; e < EPT; ++e) {
    int b = (int)(bo[e] >> 16);
    int lo = (int)cnt16[b], hi = (int)cnt16[b + 1];
    int hm1 = hi - 1;
    u64 k = key[e];
    u64 p0 = pairs[lo];
    u64 p1 = pairs[lo + 1 < hm1 ? lo + 1 : hm1];
    u64 p2 = pairs[lo + 2 < hm1 ? lo + 2 : hm1];
    u64 p3 = pairs[lo + 3 < hm1 ? lo + 3 : hm1];
    int n = hi - lo;
    int r = (int)(p0 < k) + (int)(n > 1 && p1 < k)
          + (int)(n > 2 && p2 < k) + (int)(n > 3 && p3 < k);
    if (n > 4) {                       // rare: bucket larger than 4
      for (int j2 = lo + 4; j2 < hi; ++j2) r += (int)(pairs[j2] < k);
    }
    dst[e] = lo + r;
  }
  // issue own-w reloads (coalesced, L2-resident); latency hides under barrier
  float4 wv0 = wr4[tid * 2], wv1 = wr4[tid * 2 + 1];
  __syncthreads();   // [6] all pairs reads done before aliasing xs/wy writes

  // ---- scatter (x, w) directly to sorted slots (no sorted-pairs pass,
  //      no global gather); consume each float4 immediately ----
  xs[dst[0]] = __uint_as_float((u32)(key[0] >> 32)); wy[swz(dst[0])] = wv0.x;
  xs[dst[1]] = __uint_as_float((u32)(key[1] >> 32)); wy[swz(dst[1])] = wv0.y;
  xs[dst[2]] = __uint_as_float((u32)(key[2] >> 32)); wy[swz(dst[2])] = wv0.z;
  xs[dst[3]] = __uint_as_float((u32)(key[3] >> 32)); wy[swz(dst[3])] = wv0.w;
  xs[dst[4]] = __uint_as_float((u32)(key[4] >> 32)); wy[swz(dst[4])] = wv1.x;
  xs[dst[5]] = __uint_as_float((u32)(key[5] >> 32)); wy[swz(dst[5])] = wv1.y;
  xs[dst[6]] = __uint_as_float((u32)(key[6] >> 32)); wy[swz(dst[6])] = wv1.z;
  xs[dst[7]] = __uint_as_float((u32)(key[7] >> 32)); wy[swz(dst[7])] = wv1.w;
  __syncthreads();   // [7] sorted xs/w visible

  // ---- cumsum weights (read own 8 sorted slots, swizzled = conflict-free) ----
  float lw[EPT];
  float runf = 0.f;
#pragma unroll
  for (int c = 0; c < EPT; ++c) {
    float wv = wy[swz(8 * tid + c)];
    runf += wv; lw[c] = runf;
  }
  float totf = runf, pref = runf;
#pragma unroll
  for (int off = 1; off < 64; off <<= 1) {
    float v = __shfl_up(pref, off);
    if (lane >= off) pref += v;
  }
  if (lane == 63) fwt[wave] = pref;
  __syncthreads();   // [8] fwt visible
  float wpf = 0.f;
#pragma unroll
  for (int w2 = 0; w2 < NW; ++w2) wpf += (w2 < wave) ? fwt[w2] : 0.f;
  float basef = wpf + pref - totf;
#pragma unroll
  for (int c = 0; c < EPT; ++c) wy[swz(8 * tid + c)] = basef + lw[c];
  __syncthreads();   // [9] xs + CDF visible

  // ---- stage 1: ecdf values into REGISTERS (bucket bases = exact brackets) ----
  // Predicated count over the (sorted) bucket == lower_bound; inline rare tail.
  float ev[N3 / T];
#pragma unroll
  for (int s = 0; s < N3 / T; ++s) {
    int j = tid + s * T;
    float xnew = -1.0f + (3.0f * (float)j) / 3071.0f;
    float ix = floorf(xnew);
    float rest = xnew - ix;                      // in [0,1)
    int k = (int)(rest * (float)NB);             // exact
    k = k > NB - 1 ? NB - 1 : k;
    int lo = (int)cnt16[k], hi = (int)cnt16[k + 1];
    int n = hi - lo;
    const int hc = NCOL - 1;
    float a0 = xs[lo + 0 < hc ? lo + 0 : hc];
    float a1 = xs[lo + 1 < hc ? lo + 1 : hc];
    float a2 = xs[lo + 2 < hc ? lo + 2 : hc];
    float a3 = xs[lo + 3 < hc ? lo + 3 : hc];
    int c = (int)(n > 0 && a0 < rest) + (int)(n > 1 && a1 < rest)
          + (int)(n > 2 && a2 < rest) + (int)(n > 3 && a3 < rest);
    int lb = lo + c;
    if (n > 4 && c == 4) {                       // rare: first 4 all < rest
      int p = lo + 4;
      while (p < hi && xs[p] < rest) ++p;
      lb = p;
    }
    int ind = lb - 1;
    ind = ind < 0 ? 0 : (ind > NCOL - 2 ? NCOL - 2 : ind);
    float x0 = xs[ind], x1v = xs[ind + 1];
    float y0 = wy[swz(ind)], y1v = wy[swz(ind + 1)];
    float slope = (y1v - y0) * __builtin_amdgcn_rcpf(FEPS + (x1v - x0));
    ev[s] = ix + (y0 + slope * (rest - x0));
  }
  __syncthreads();   // [10] all xs/wy reads done -> wy region reusable

  // ---- write ecdf overlay (over dead wy region) ----
#pragma unroll
  for (int s = 0; s < N3 / T; ++s) ecdf[tid + s * T] = ev[s];
  __syncthreads();   // [11]

  // ---- stage-2 value LUT over ecdf range [-1,2): 257 brackets ----
  if (tid < 257) {
    float v = -1.0f + 3.0f * (float)tid * (1.0f / 256.0f);
    lut2[tid] = (u16)lower_bound_f(ecdf, 0, N3, v);
  }
  __syncthreads();   // [12]

  // ---- stage 2: inverse-CDF embedding + circular cost partial sum ----
  float alpha = s_alpha;
  float accf = 0.f;
#pragma unroll
  for (int s = 0; s < NG / T; ++s) {
    int kq = tid + s * T;
    float xg = (float)kq / 1024.0f;
    float q2 = xg - alpha;
    int k2 = (int)floorf((q2 + 1.0f) * (256.0f / 3.0f));
    k2 = k2 < 0 ? 0 : (k2 > 255 ? 255 : k2);
    int blo = k2 > 0 ? k2 - 1 : 0;           // widen +-1: immune to fp rounding of k2
    int bhi = k2 < 254 ? k2 + 2 : 256;
    int lo = lower_bound_f(ecdf, (int)lut2[blo], (int)lut2[bhi], q2);
    int ind = lo - 1;
    ind = ind < 0 ? 0 : (ind > N3 - 2 ? N3 - 2 : ind);
    float e0 = ecdf[ind], e1 = ecdf[ind + 1];
    float y0 = -1.0f + (3.0f * (float)ind) / 3071.0f;
    float y1 = -1.0f + (3.0f * (float)(ind + 1)) / 3071.0f;
    float slope = (y1 - y0) * __builtin_amdgcn_rcpf(FEPS + (e1 - e0));
    float emb = y0 + slope * (q2 - e0) - xg;
    float a = fabsf(emb);
    float m = fminf(a, 1.0f - a);
    accf += m * m;
  }
#pragma unroll
  for (int off = 32; off > 0; off >>= 1) accf += __shfl_down(accf, off);
  if (lane == 0) redA[wave] = accf;
  __syncthreads();   // [13]
  if (tid == 0) {
    float s = 0.f;
#pragma unroll
    for (int i = 0; i < NW; ++i) s += redA[i];
    rowsum[row] = s;
  }
}

__global__ __launch_bounds__(256) void lcot_final(const float* __restrict__ rowsum,
                                                  float* __restrict__ out) {
  __shared__ float red[4];
  int t = threadIdx.x;
  float s = 0.f;
  for (int i = t; i < L; i += 256) s += rowsum[i];
#pragma unroll
  for (int off = 32; off > 0; off >>= 1) s += __shfl_down(s, off);
  if ((t & 63) == 0) red[t >> 6] = s;
  __syncthreads();
  if (t == 0) {
    float tot = red[0] + red[1] + red[2] + red[3];
    out[0] = sqrtf(tot / (float)L + 1e-8f);
  }
}

extern "C" void kernel_launch(void* const* d_in, const int* in_sizes, int n_in,
                              void* d_out, int out_size, void* d_ws, size_t ws_size,
                              hipStream_t stream) {
  const float* X = (const float*)d_in[0];
  const float* W = (const float*)d_in[1];
  float* rowsum = (float*)d_ws;  // 2048 floats
  // 32768 (pairs/xs/wy, ecdf overlays wy) + 4104 (u16 cnt) + 520 (lut2) = 37,392 B
  size_t shbytes = 32768 + 4104 + 520;
  hipLaunchKernelGGL(lcot_rows, dim3(L), dim3(T), shbytes, stream, X, W, rowsum);
  hipLaunchKernelGGL(lcot_final, dim3(1), dim3(256), 0, stream,
                     (const float*)rowsum, (float*)d_out);
}

// Round 3
// 181.942 us; speedup vs baseline: 1.2350x; 1.0580x over previous
//
#include <hip/hip_runtime.h>
#include <math.h>

#define L    2048
#define NCOL 4096
#define NG   1024
#define N3   3072
#define T    512
#define NW   8            // waves per block
#define EPT  8            // NCOL / T
#define NB   2048         // buckets (exact: floor(x*2048), power-of-two mult)
#define FEPS 1.1920929e-07f

typedef unsigned long long u64;
typedef unsigned short u16;
typedef unsigned int u32;

__device__ __forceinline__ int lower_bound_f(const float* a, int lo, int hi, float v) {
  // exact replica of numpy's npy_binsearch (side='left') on [lo,hi)
  while (lo < hi) {
    int mid = (lo + hi) >> 1;
    if (a[mid] < v) lo = mid + 1; else hi = mid;
  }
  return lo;
}

__device__ __forceinline__ int bucket_of_bits(unsigned xb) {
  float f = __uint_as_float(xb);
  int b = (int)(f * (float)NB);          // exact: mult by 2^11
  return b > NB - 1 ? NB - 1 : b;
}

// XOR swizzle for the w/y plane. Blocked access wy[swz(8t+c)] at fixed c:
// addr%32 = (8(t%4) + (c ^ ((t>>2)&7))) % 32 -> each bank hit exactly 2x
// per 64 lanes (2-way = free, m136). Bijective (bits0-2 ^= bits5-7).
__device__ __forceinline__ int swz(int i) { return i ^ ((i >> 5) & 7); }

// LDS layout (37,392 B dynamic -> 4 blocks/CU, 32 waves/CU):
//   [0,32768)      pairs u64[4096]; aliased later: xs f32[4096] @0,
//                  wy f32[4096] @16384 (sorted w, then in-place CDF ys, swizzled)
//   [16384,28672)  ecdf f32[3072] overlays wy AFTER stage-1 (wy dead by then)
//   [32768,36872)  cnt u16[2050] (packed u32 words for atomics), padded
//   [36872,37392)  lut2 u16[257]
__global__ __launch_bounds__(T, 8) void lcot_rows(const float* __restrict__ X,
                                                  const float* __restrict__ W,
                                                  float* __restrict__ rowsum) {
  extern __shared__ char smem[];
  u64*   pairs = (u64*)smem;
  float* xs    = (float*)smem;
  float* wy    = (float*)(smem + 16384);
  float* ecdf  = (float*)(smem + 16384);          // overlay, used after stage-1
  u16*   cnt16 = (u16*)(smem + 32768);
  u32*   cntw  = (u32*)(smem + 32768);
  u16*   lut2  = (u16*)(smem + 36872);

  __shared__ float redA[NW], redB[NW], fwt[NW];
  __shared__ int   iwt[NW];
  __shared__ float s_alpha;

  const int tid  = threadIdx.x;
  const int lane = tid & 63;
  const int wave = tid >> 6;
  const int row  = blockIdx.x;
  const float* xr = X + (size_t)row * NCOL;
  const float* wr = W + (size_t)row * NCOL;

  // ---- zero packed histogram (1025 u32 words incl. sentinel word) ----
  for (int i = tid; i < 1025; i += T) cntw[i] = 0u;

  // ---- load 8 consecutive elems, pack stable keys, alpha partials ----
  u64 key[EPT];
  float sxw = 0.f, sw = 0.f;
  const float4* xr4 = (const float4*)xr;
  const float4* wr4 = (const float4*)wr;
#pragma unroll
  for (int c = 0; c < 2; ++c) {
    float4 xv = xr4[tid * 2 + c];
    float4 ww = wr4[tid * 2 + c];
    sxw += xv.x * ww.x + xv.y * ww.y + xv.z * ww.z + xv.w * ww.w;
    sw  += ww.x + ww.y + ww.z + ww.w;
    int b = 8 * tid + 4 * c;
    key[4*c+0] = ((u64)__float_as_uint(xv.x) << 32) | (unsigned)(b + 0);
    key[4*c+1] = ((u64)__float_as_uint(xv.y) << 32) | (unsigned)(b + 1);
    key[4*c+2] = ((u64)__float_as_uint(xv.z) << 32) | (unsigned)(b + 2);
    key[4*c+3] = ((u64)__float_as_uint(xv.w) << 32) | (unsigned)(b + 3);
  }
#pragma unroll
  for (int off = 32; off > 0; off >>= 1) {
    sxw += __shfl_down(sxw, off);
    sw  += __shfl_down(sw, off);
  }
  if (lane == 0) { redA[wave] = sxw; redB[wave] = sw; }
  __syncthreads();   // [1] zeroed cnt + redA/redB visible

  // ---- histogram on packed u16 fields; pack (bucket, ord) into one word ----
  u32 bo[EPT];
#pragma unroll
  for (int e = 0; e < EPT; ++e) {
    int b = bucket_of_bits((unsigned)(key[e] >> 32));
    u32 inc = (b & 1) ? 65536u : 1u;
    u32 ret = atomicAdd(&cntw[b >> 1], inc);
    u32 o = (b & 1) ? (ret >> 16) : (ret & 0xffffu);
    bo[e] = ((u32)b << 16) | (o & 0xffffu);
  }
  __syncthreads();   // [2] all atomics done
  if (tid == 0) {
    float a = 0.f, b = 0.f;
#pragma unroll
    for (int i = 0; i < NW; ++i) { a += redA[i]; b += redB[i]; }
    s_alpha = a / b - 0.5f;
  }

  // ---- exclusive scan of 2048 u16 counts -> bases (packed, in place) ----
  u32 cv0 = cntw[2 * tid], cv1 = cntw[2 * tid + 1];
  int c0 = (int)(cv0 & 0xffffu), c1 = (int)(cv0 >> 16);
  int c2 = (int)(cv1 & 0xffffu), c3 = (int)(cv1 >> 16);
  int runi = c0 + c1 + c2 + c3;
  int toti = runi, prei = runi;
#pragma unroll
  for (int off = 1; off < 64; off <<= 1) {
    int v = __shfl_up(prei, off);
    if (lane >= off) prei += v;
  }
  if (lane == 63) iwt[wave] = prei;
  __syncthreads();   // [3] iwt visible (each thread only rewrites its own words)
  int wpre = 0;
#pragma unroll
  for (int w2 = 0; w2 < NW; ++w2) wpre += (w2 < wave) ? iwt[w2] : 0;
  int acc = wpre + prei - toti;
  {
    int b0 = acc; acc += c0;
    int b1 = acc; acc += c1;
    int b2 = acc; acc += c2;
    int b3 = acc; acc += c3;
    cntw[2 * tid]     = (u32)b0 | ((u32)b1 << 16);
    cntw[2 * tid + 1] = (u32)b2 | ((u32)b3 << 16);
  }
  if (tid == T - 1) cnt16[NB] = (u16)acc;   // sentinel = 4096
  __syncthreads();   // [4] bases visible

  // ---- scatter keys into bucket slots (arrival order) ----
#pragma unroll
  for (int e = 0; e < EPT; ++e) {
    int b = (int)(bo[e] >> 16);
    int o = (int)(bo[e] & 0xffffu);
    pairs[(int)cnt16[b] + o] = key[e];
  }
  __syncthreads();   // [5]

  // ---- per-bucket insertion sort in LDS (4 buckets/thread, disjoint slots) ----
  // strict u64 order (xbits, idx) == exact stable argsort
#pragma unroll
  for (int bb = 0; bb < 4; ++bb) {
    int b  = 4 * tid + bb;
    int lo = (int)cnt16[b], hi = (int)cnt16[b + 1];
    for (int i = lo + 1; i < hi; ++i) {
      u64 v = pairs[i];
      int j = i - 1;
      while (j >= lo && pairs[j] > v) { pairs[j + 1] = pairs[j]; --j; }
      pairs[j + 1] = v;
    }
  }
  __syncthreads();   // [6] pairs fully sorted

  // ---- finish pass, CYCLIC ownership (j = tid + 512m): conflict-free.
  //      pairs[j] read: dword addr 2(t+512m) -> quarters tile banks (free),
  //      vs the old blocked ulonglong2 re-read (stride 64B -> 16-way/quarter,
  //      ~2000 conflict-cycles/block = the baseline's dominant conflict). ----
  u64 q[EPT];
#pragma unroll
  for (int m = 0; m < EPT; ++m) q[m] = pairs[tid + m * T];
  float wg[EPT];
#pragma unroll
  for (int m = 0; m < EPT; ++m) wg[m] = wr[(u32)(q[m] & 0xffffffffu)];
  __syncthreads();   // [7] all pairs reads done before aliasing xs/wy writes

#pragma unroll
  for (int m = 0; m < EPT; ++m) {
    int j = tid + m * T;
    xs[j]      = __uint_as_float((u32)(q[m] >> 32));   // bank t%32: free
    wy[swz(j)] = wg[m];                                 // ~2-way: free
  }
  __syncthreads();   // [8] sorted xs + w visible

  // ---- cumsum weights (blocked read of own 8 sorted slots, swizzled=free;
  //      identical per-thread summation order as the register version) ----
  float lw[EPT];
  float runf = 0.f;
#pragma unroll
  for (int c = 0; c < EPT; ++c) {
    runf += wy[swz(8 * tid + c)];
    lw[c] = runf;
  }
  float totf = runf, pref = runf;
#pragma unroll
  for (int off = 1; off < 64; off <<= 1) {
    float v = __shfl_up(pref, off);
    if (lane >= off) pref += v;
  }
  if (lane == 63) fwt[wave] = pref;
  __syncthreads();   // [9] fwt visible
  float wpf = 0.f;
#pragma unroll
  for (int w2 = 0; w2 < NW; ++w2) wpf += (w2 < wave) ? fwt[w2] : 0.f;
  float basef = wpf + pref - totf;
#pragma unroll
  for (int c = 0; c < EPT; ++c) wy[swz(8 * tid + c)] = basef + lw[c];
  __syncthreads();   // [10] xs + CDF visible

  // ---- stage 1: ecdf values into REGISTERS (bucket bases = exact brackets) ----
  float ev[N3 / T];
#pragma unroll
  for (int s = 0; s < N3 / T; ++s) {
    int j = tid + s * T;
    float xnew = -1.0f + (3.0f * (float)j) / 3071.0f;
    float ix = floorf(xnew);
    float rest = xnew - ix;                  // in [0,1)
    int k = (int)(rest * (float)NB);         // exact
    k = k > NB - 1 ? NB - 1 : k;
    int lo = lower_bound_f(xs, (int)cnt16[k], (int)cnt16[k + 1], rest);
    int ind = lo - 1;
    ind = ind < 0 ? 0 : (ind > NCOL - 2 ? NCOL - 2 : ind);
    float x0 = xs[ind], x1v = xs[ind + 1];
    float y0 = wy[swz(ind)], y1v = wy[swz(ind + 1)];
    float slope = (y1v - y0) * __builtin_amdgcn_rcpf(FEPS + (x1v - x0));
    ev[s] = ix + (y0 + slope * (rest - x0));
  }
  __syncthreads();   // [11] all xs/wy reads done -> wy region reusable

  // ---- write ecdf overlay (over dead wy region) ----
#pragma unroll
  for (int s = 0; s < N3 / T; ++s) ecdf[tid + s * T] = ev[s];
  __syncthreads();   // [12]

  // ---- stage-2 value LUT over ecdf range [-1,2): 257 brackets ----
  if (tid < 257) {
    float v = -1.0f + 3.0f * (float)tid * (1.0f / 256.0f);
    lut2[tid] = (u16)lower_bound_f(ecdf, 0, N3, v);
  }
  __syncthreads();   // [13]

  // ---- stage 2: inverse-CDF embedding + circular cost partial sum ----
  float alpha = s_alpha;
  float accf = 0.f;
#pragma unroll
  for (int s = 0; s < NG / T; ++s) {
    int kq = tid + s * T;
    float xg = (float)kq / 1024.0f;
    float q2 = xg - alpha;
    int k2 = (int)floorf((q2 + 1.0f) * (256.0f / 3.0f));
    k2 = k2 < 0 ? 0 : (k2 > 255 ? 255 : k2);
    int blo = k2 > 0 ? k2 - 1 : 0;           // widen +-1: immune to fp rounding of k2
    int bhi = k2 < 254 ? k2 + 2 : 256;
    int lo = lower_bound_f(ecdf, (int)lut2[blo], (int)lut2[bhi], q2);
    int ind = lo - 1;
    ind = ind < 0 ? 0 : (ind > N3 - 2 ? N3 - 2 : ind);
    float e0 = ecdf[ind], e1 = ecdf[ind + 1];
    float y0 = -1.0f + (3.0f * (float)ind) / 3071.0f;
    float y1 = -1.0f + (3.0f * (float)(ind + 1)) / 3071.0f;
    float slope = (y1 - y0) * __builtin_amdgcn_rcpf(FEPS + (e1 - e0));
    float emb = y0 + slope * (q2 - e0) - xg;
    float a = fabsf(emb);
    float m = fminf(a, 1.0f - a);
    accf += m * m;
  }
#pragma unroll
  for (int off = 32; off > 0; off >>= 1) accf += __shfl_down(accf, off);
  if (lane == 0) redA[wave] = accf;
  __syncthreads();   // [14]
  if (tid == 0) {
    float s = 0.f;
#pragma unroll
    for (int i = 0; i < NW; ++i) s += redA[i];
    rowsum[row] = s;
  }
}

__global__ __launch_bounds__(256) void lcot_final(const float* __restrict__ rowsum,
                                                  float* __restrict__ out) {
  __shared__ float red[4];
  int t = threadIdx.x;
  float s = 0.f;
  for (int i = t; i < L; i += 256) s += rowsum[i];
#pragma unroll
  for (int off = 32; off > 0; off >>= 1) s += __shfl_down(s, off);
  if ((t & 63) == 0) red[t >> 6] = s;
  __syncthreads();
  if (t == 0) {
    float tot = red[0] + red[1] + red[2] + red[3];
    out[0] = sqrtf(tot / (float)L + 1e-8f);
  }
}

extern "C" void kernel_launch(void* const* d_in, const int* in_sizes, int n_in,
                              void* d_out, int out_size, void* d_ws, size_t ws_size,
                              hipStream_t stream) {
  const float* X = (const float*)d_in[0];
  const float* W = (const float*)d_in[1];
  float* rowsum = (float*)d_ws;  // 2048 floats
  // 32768 (pairs/xs/wy, ecdf overlays wy) + 4104 (u16 cnt) + 520 (lut2) = 37,392 B
  size_t shbytes = 32768 + 4104 + 520;
  hipLaunchKernelGGL(lcot_rows, dim3(L), dim3(T), shbytes, stream, X, W, rowsum);
  hipLaunchKernelGGL(lcot_final, dim3(1), dim3(256), 0, stream,
                     (const float*)rowsum, (float*)d_out);
}